// Round 23
// baseline (67.275 us; speedup 1.0000x reference)
//
#include <hip/hip_runtime.h>

#define KS 63
#define PAD 31
#define R 16   // hblur / fallback tile factor
#define RV 8   // fused vblur+warp: outputs per thread (32-row tiles)

typedef float f32x2 __attribute__((ext_vector_type(2)));

// ---------------------------------------------------------------------------
// Compile-time Gaussian weights (normalized, double precision -> f32 literals)
// ---------------------------------------------------------------------------
constexpr double cexp_neg(double t) {  // e^{-t}, t in [0, 0.47]
    double s = 1.0, term = 1.0;
    for (int i = 1; i < 24; ++i) { term *= (-t) / (double)i; s += term; }
    return s;
}
struct WTab { float w[KS]; };
constexpr WTab make_wtab() {
    WTab r{};
    double v[KS] = {}; double s = 0.0;
    for (int i = 0; i < KS; ++i) {
        double x = (double)(i - PAD);
        v[i] = cexp_neg((x * x) / 2048.0);   // 2*sigma^2 = 2048
        s += v[i];
    }
    for (int i = 0; i < KS; ++i) r.w[i] = (float)(v[i] / s);
    return r;
}
constexpr WTab WT = make_wtab();

// ---------------------------------------------------------------------------
// Horizontal blur, transposed-tile. Block = 64 rows x 64 out cols.
// float4 staging (8 loads/thread). Zero-padding applies AFTER the (n*2-1)
// map — OOB halo must be 0, not -1. (R15/R16 proven version, byte-identical)
// ---------------------------------------------------------------------------
__global__ __launch_bounds__(256) void hblur_kernel(const float* __restrict__ noise,
                                                    float* __restrict__ tmp,
                                                    int H, int W) {
    __shared__ float st[128][65];   // [c][row]; input col = x0-32+c
    const int tid = threadIdx.x;
    const int x0 = blockIdx.x * 64;
    const int y0 = blockIdx.y * 64;
    const int bc = blockIdx.z;              // b*2 + ch
    const int base = bc * H * W;

    // stage 64 rows x 128 cols as float4 (8/thread), transposed into LDS
    for (int i = tid; i < 64 * 32; i += 256) {
        int row = i >> 5;
        int c4 = i & 31;                    // covers input cols c4*4 .. c4*4+3
        int gx = x0 - 32 + c4 * 4;          // multiple of 4 -> aligned or fully OOB
        const float* src = noise + base + (y0 + row) * W + gx;
        float4 m;
        if (gx >= 0 && gx <= W - 4) {
            float4 v = *(const float4*)src;
            m.x = v.x * 2.0f - 1.0f;
            m.y = v.y * 2.0f - 1.0f;
            m.z = v.z * 2.0f - 1.0f;
            m.w = v.w * 2.0f - 1.0f;
        } else {
            m.x = ((unsigned)(gx + 0) < (unsigned)W) ? src[0] * 2.0f - 1.0f : 0.0f;
            m.y = ((unsigned)(gx + 1) < (unsigned)W) ? src[1] * 2.0f - 1.0f : 0.0f;
            m.z = ((unsigned)(gx + 2) < (unsigned)W) ? src[2] * 2.0f - 1.0f : 0.0f;
            m.w = ((unsigned)(gx + 3) < (unsigned)W) ? src[3] * 2.0f - 1.0f : 0.0f;
        }
        const int c = c4 * 4;
        st[c + 0][row] = m.x;
        st[c + 1][row] = m.y;
        st[c + 2][row] = m.z;
        st[c + 3][row] = m.w;
    }
    __syncthreads();

    const int tx = tid & 63;    // row lane (stride-1 LDS reads)
    const int ty = tid >> 6;    // col strip 0..3
    float acc[R];
#pragma unroll
    for (int o = 0; o < R; ++o) acc[o] = 0.0f;

    const int cbase = ty * R + 1;
#pragma unroll
    for (int t = 0; t < R + KS - 1; ++t) {
        float v = st[cbase + t][tx];
#pragma unroll
        for (int o = 0; o < R; ++o) {
            int k = t - o;
            if (k >= 0 && k < KS) acc[o] += WT.w[k] * v;
        }
    }
    __syncthreads();

    // transpose outputs back through LDS (reuse st) for coalesced stores
    float* so = &st[0][0];      // logical [64][65]
#pragma unroll
    for (int o = 0; o < R; ++o)
        so[tx * 65 + ty * R + o] = acc[o];
    __syncthreads();
    for (int i = tid; i < 64 * 16; i += 256) {
        int row = i >> 4;
        int c4 = i & 15;
        const float* sp = &so[row * 65 + c4 * 4];
        float4 v; v.x = sp[0]; v.y = sp[1]; v.z = sp[2]; v.w = sp[3];
        *(float4*)(tmp + base + (y0 + row) * W + x0 + c4 * 4) = v;
    }
}

// ---------------------------------------------------------------------------
// Per-pixel sampler (fallback kernels only)
// ---------------------------------------------------------------------------
__device__ __forceinline__ void sample_and_store(const float* __restrict__ img,
                                                 float* __restrict__ out,
                                                 int ibase, int HW,
                                                 int y, int x, int H, int W,
                                                 float dx, float dy) {
    const float gx = -1.0f + (float)x * (2.0f / (W - 1));
    const float gy = -1.0f + (float)y * (2.0f / (H - 1));
    const float sx = fminf(fmaxf(gx + dx, -1.0f), 1.0f);
    const float sy = fminf(fmaxf(gy + dy, -1.0f), 1.0f);
    const float ix = ((sx + 1.0f) * (float)W - 1.0f) * 0.5f;
    const float iy = ((sy + 1.0f) * (float)H - 1.0f) * 0.5f;
    const float ix0f = floorf(ix);
    const float iy0f = floorf(iy);
    const int ix0 = (int)ix0f;
    const int iy0 = (int)iy0f;
    const float wx = ix - ix0f;
    const float wy = iy - iy0f;

    const float bx0 = (ix0 == -1) ? wx : ((ix0 <= W - 2) ? (1.0f - wx) : 0.0f);
    const float bx1 = (ix0 >= W - 1) ? (1.0f - wx) : ((ix0 >= 0) ? wx : 0.0f);
    const float ay0 = (iy0 >= 0) ? (1.0f - wy) : 0.0f;
    const float ay1 = (iy0 <= H - 2) ? wy : 0.0f;
    const int px = min(max(ix0, 0), W - 2);
    const int it = min(max(iy0, 0), H - 1) * W + px;
    const int ib = min(max(iy0 + 1, 0), H - 1) * W + px;
    const int orem = y * W + x;

#pragma unroll
    for (int c = 0; c < 3; ++c) {
        const float* p = img + ibase + c * HW;
        f32x2 t, bt;
        __builtin_memcpy(&t,  p + it, 8);
        __builtin_memcpy(&bt, p + ib, 8);
        const float rt = t.x * bx0 + t.y * bx1;
        const float rb = bt.x * bx0 + bt.y * bx1;
        __builtin_nontemporal_store(rt * ay0 + rb * ay1, &out[ibase + c * HW + orem]);
    }
}

// shared conv body (compile-time indices; s is one channel's LDS tile)
__device__ __forceinline__ void conv_col(const float (*__restrict__ s)[64],
                                         int yr, int tx, float acc[RV]) {
#pragma unroll
    for (int o = 0; o < RV; ++o) acc[o] = 0.0f;
#pragma unroll
    for (int t = 0; t < RV + KS - 1; ++t) {
        float v = s[yr + t][tx];
#pragma unroll
        for (int o = 0; o < RV; ++o) {
            int k = t - o;
            if (k >= 0 && k < KS) acc[o] += WT.w[k] * v;
        }
    }
}

// ---------------------------------------------------------------------------
// FUSED vertical blur + warp: tmp[B,2,H,W] -> disp[B,H,W,2] + warped[B,3,H,W]
// Block = 32 rows x 64 cols (RV=8); chunked XCD swizzle; batched gather.
// R23: dual LDS buffer (48.1 KB) — both channels staged back-to-back with all
// 12 float4 loads in flight, then ONE barrier (was 3), conv ch0 + conv ch1
// back-to-back, then gather.
// ---------------------------------------------------------------------------
__global__ __launch_bounds__(256) void vblur_warp_kernel(const float* __restrict__ tmp,
                                                         const float* __restrict__ img,
                                                         float* __restrict__ disp,
                                                         float* __restrict__ warped,
                                                         int H, int W) {
    constexpr int SROWS = 4 * RV + KS - 1;     // 94
    __shared__ float s[2][SROWS][64];          // 48.13 KB
    const int tid = threadIdx.x;

    // chunked XCD swizzle: XCD k gets consecutive logical tiles (2 images)
    const int nx = gridDim.x, ny = gridDim.y;
    const int nwg = nx * ny * gridDim.z;           // 2048, % 8 == 0
    const int flat = blockIdx.x + nx * (blockIdx.y + ny * blockIdx.z);
    const int wg = (flat & 7) * (nwg >> 3) + (flat >> 3);
    const int xt = wg % nx;
    const int yt = (wg / nx) % ny;
    const int b  = wg / (nx * ny);

    const int x0 = xt * 64;
    const int y0 = yt * (4 * RV);
    const int tx = tid & 63;
    const int ty = tid >> 6;
    const int yr = ty * RV;
    const int HW = H * W;

    // ---- stage BOTH channels; all loads issue before the single barrier ----
#pragma unroll
    for (int ch = 0; ch < 2; ++ch) {
        const int base = (b * 2 + ch) * HW;
        float4* s4 = (float4*)&s[ch][0][0];
        for (int i = tid; i < SROWS * 16; i += 256) {
            int row = i >> 4;
            int c4 = i & 15;
            int gy = y0 + row - PAD;
            float4 v = make_float4(0.0f, 0.0f, 0.0f, 0.0f);
            if (gy >= 0 && gy < H) v = *(const float4*)(tmp + base + gy * W + x0 + c4 * 4);
            s4[row * 16 + c4] = v;
        }
    }
    __syncthreads();            // the ONLY barrier

    // ---- conv both channels, no intervening syncs (distinct buffers) ----
    float acc0[RV], acc1[RV];
    conv_col(s[0], yr, tx, acc0);
    conv_col(s[1], yr, tx, acc1);

    const int x = x0 + tx;
    const int ibase = b * 3 * HW;
    f32x2* disp2 = (f32x2*)disp;

    // ---- phase 1: all per-pixel params (no loads) ----
    float BX0[RV], BX1[RV], AY0[RV], AY1[RV];
    int IT[RV], IB[RV];
    const float gxn = -1.0f + (float)x * (2.0f / (W - 1));
#pragma unroll
    for (int o = 0; o < RV; ++o) {
        const int y = y0 + yr + o;
        const float dx = acc0[o];
        const float dy = acc1[o];
        f32x2 dv; dv.x = dx; dv.y = dy;
        __builtin_nontemporal_store(dv, &disp2[(b * H + y) * W + x]);

        const float gyn = -1.0f + (float)y * (2.0f / (H - 1));
        const float sx = fminf(fmaxf(gxn + dx, -1.0f), 1.0f);
        const float sy = fminf(fmaxf(gyn + dy, -1.0f), 1.0f);
        const float ix = ((sx + 1.0f) * (float)W - 1.0f) * 0.5f;
        const float iy = ((sy + 1.0f) * (float)H - 1.0f) * 0.5f;
        const float ix0f = floorf(ix);
        const float iy0f = floorf(iy);
        const int ix0 = (int)ix0f;
        const int iy0 = (int)iy0f;
        const float wx = ix - ix0f;
        const float wy = iy - iy0f;

        BX0[o] = (ix0 == -1) ? wx : ((ix0 <= W - 2) ? (1.0f - wx) : 0.0f);
        BX1[o] = (ix0 >= W - 1) ? (1.0f - wx) : ((ix0 >= 0) ? wx : 0.0f);
        AY0[o] = (iy0 >= 0) ? (1.0f - wy) : 0.0f;
        AY1[o] = (iy0 <= H - 2) ? wy : 0.0f;
        const int px = min(max(ix0, 0), W - 2);
        IT[o] = min(max(iy0, 0), H - 1) * W + px;
        IB[o] = min(max(iy0 + 1, 0), H - 1) * W + px;
    }

    // ---- phases 2+3 per channel: issue ALL 16 loads, then combine ----
#pragma unroll
    for (int c = 0; c < 3; ++c) {
        const float* p = img + ibase + c * HW;
        f32x2 T[RV], Bt[RV];
#pragma unroll
        for (int o = 0; o < RV; ++o) {
            __builtin_memcpy(&T[o],  p + IT[o], 8);
            __builtin_memcpy(&Bt[o], p + IB[o], 8);
        }
#pragma unroll
        for (int o = 0; o < RV; ++o) {
            const float rt = T[o].x * BX0[o] + T[o].y * BX1[o];
            const float rb = Bt[o].x * BX0[o] + Bt[o].y * BX1[o];
            const float v = rt * AY0[o] + rb * AY1[o];
            const int y = y0 + yr + o;
            __builtin_nontemporal_store(v, &warped[ibase + c * HW + y * W + x]);
        }
    }
}

// ---------------------------------------------------------------------------
// Fallback pair (used only if d_ws is too small to hold tmp)
// ---------------------------------------------------------------------------
__global__ __launch_bounds__(256) void vblur_kernel(const float* __restrict__ tmp,
                                                    float* __restrict__ disp,
                                                    int H, int W) {
    __shared__ float s[126][64];
    const int tid = threadIdx.x;
    const int x0 = blockIdx.x * 64;
    const int y0 = blockIdx.y * 64;
    const int b = blockIdx.z;
    const int tx = tid & 63;
    const int ty = tid >> 6;
    const int yr = ty * R;
    float acc0[R], acc1[R];

#pragma unroll
    for (int ch = 0; ch < 2; ++ch) {
        __syncthreads();
        const int base = (b * 2 + ch) * H * W;
        float2* s2 = (float2*)&s[0][0];
        for (int i = tid; i < 126 * 32; i += 256) {
            int row = i >> 5;
            int c2 = i & 31;
            int gy = y0 + row - PAD;
            float2 v = make_float2(0.0f, 0.0f);
            if (gy >= 0 && gy < H) v = *(const float2*)(tmp + base + gy * W + x0 + c2 * 2);
            s2[row * 32 + c2] = v;
        }
        __syncthreads();

        float* acc = (ch == 0) ? acc0 : acc1;
#pragma unroll
        for (int o = 0; o < R; ++o) acc[o] = 0.0f;
#pragma unroll
        for (int t = 0; t < R + KS - 1; ++t) {
            float v = s[yr + t][tx];
#pragma unroll
            for (int o = 0; o < R; ++o) {
                int k = t - o;
                if (k >= 0 && k < KS) acc[o] += WT.w[k] * v;
            }
        }
    }

    float2* disp2 = (float2*)disp;
#pragma unroll
    for (int o = 0; o < R; ++o) {
        int y = y0 + yr + o;
        disp2[(b * H + y) * W + x0 + tx] = make_float2(acc0[o], acc1[o]);
    }
}

__global__ __launch_bounds__(256) void warp_kernel(const float* __restrict__ img,
                                                   const float* __restrict__ disp,
                                                   float* __restrict__ out,
                                                   int B, int H, int W) {
    const int HW = H * W;
    const int idx = blockIdx.x * 256 + threadIdx.x;
    if (idx >= B * HW) return;
    const int b = idx / HW;
    const int rem = idx - b * HW;
    const int y = rem / W;
    const int x = rem - y * W;
    const float2 d = ((const float2*)disp)[idx];
    sample_and_store(img, out, b * 3 * HW, HW, y, x, H, W, d.x, d.y);
}

// ---------------------------------------------------------------------------
extern "C" void kernel_launch(void* const* d_in, const int* in_sizes, int n_in,
                              void* d_out, int out_size, void* d_ws, size_t ws_size,
                              hipStream_t stream) {
    const float* input = (const float*)d_in[0];   // [16,3,512,512]
    const float* noise = (const float*)d_in[1];   // [16,2,512,512]
    float* out = (float*)d_out;

    const int B = 16, H = 512, W = 512;
    const int warped_elems = B * 3 * H * W;
    const size_t tmp_bytes = (size_t)B * 2 * H * W * sizeof(float);  // 33.5 MB

    float* warped = out;
    float* disp   = out + warped_elems;           // [B,H,W,2]

    const bool ws_ok = (ws_size >= tmp_bytes);
    float* tmp = ws_ok ? (float*)d_ws : warped;

    {
        dim3 grid(W / 64, H / 64, B * 2);
        hblur_kernel<<<grid, 256, 0, stream>>>(noise, tmp, H, W);
    }
    if (ws_ok) {
        // fused vblur + warp: disp never round-trips to memory as an input
        dim3 grid(W / 64, H / (4 * RV), B);
        vblur_warp_kernel<<<grid, 256, 0, stream>>>(tmp, input, disp, warped, H, W);
    } else {
        // tmp aliases the warped region: must keep vblur (reads tmp) strictly
        // before warp (writes warped)
        dim3 grid(W / 64, H / 64, B);
        vblur_kernel<<<grid, 256, 0, stream>>>(tmp, disp, H, W);
        int nthreads = B * H * W;
        warp_kernel<<<(nthreads + 255) / 256, 256, 0, stream>>>(input, disp, warped, B, H, W);
    }
}

// Round 24
// 61.712 us; speedup vs baseline: 1.0901x; 1.0901x over previous
//
#include <hip/hip_runtime.h>

#define KS 63
#define PAD 31
#define R 16   // hblur / fallback tile factor
#define RV 8   // fused vblur+warp: outputs per thread (32-row tiles)

typedef float f32x2 __attribute__((ext_vector_type(2)));

// ---------------------------------------------------------------------------
// Compile-time Gaussian weights (normalized, double precision -> f32 literals)
// ---------------------------------------------------------------------------
constexpr double cexp_neg(double t) {  // e^{-t}, t in [0, 0.47]
    double s = 1.0, term = 1.0;
    for (int i = 1; i < 24; ++i) { term *= (-t) / (double)i; s += term; }
    return s;
}
struct WTab { float w[KS]; };
constexpr WTab make_wtab() {
    WTab r{};
    double v[KS] = {}; double s = 0.0;
    for (int i = 0; i < KS; ++i) {
        double x = (double)(i - PAD);
        v[i] = cexp_neg((x * x) / 2048.0);   // 2*sigma^2 = 2048
        s += v[i];
    }
    for (int i = 0; i < KS; ++i) r.w[i] = (float)(v[i] / s);
    return r;
}
constexpr WTab WT = make_wtab();

// ---------------------------------------------------------------------------
// Horizontal blur, transposed-tile. Block = 64 rows x 64 out cols.
// float4 staging (8 loads/thread). Zero-padding applies AFTER the (n*2-1)
// map — OOB halo must be 0, not -1. (R15/R16 proven version, byte-identical)
// ---------------------------------------------------------------------------
__global__ __launch_bounds__(256) void hblur_kernel(const float* __restrict__ noise,
                                                    float* __restrict__ tmp,
                                                    int H, int W) {
    __shared__ float st[128][65];   // [c][row]; input col = x0-32+c
    const int tid = threadIdx.x;
    const int x0 = blockIdx.x * 64;
    const int y0 = blockIdx.y * 64;
    const int bc = blockIdx.z;              // b*2 + ch
    const int base = bc * H * W;

    // stage 64 rows x 128 cols as float4 (8/thread), transposed into LDS
    for (int i = tid; i < 64 * 32; i += 256) {
        int row = i >> 5;
        int c4 = i & 31;                    // covers input cols c4*4 .. c4*4+3
        int gx = x0 - 32 + c4 * 4;          // multiple of 4 -> aligned or fully OOB
        const float* src = noise + base + (y0 + row) * W + gx;
        float4 m;
        if (gx >= 0 && gx <= W - 4) {
            float4 v = *(const float4*)src;
            m.x = v.x * 2.0f - 1.0f;
            m.y = v.y * 2.0f - 1.0f;
            m.z = v.z * 2.0f - 1.0f;
            m.w = v.w * 2.0f - 1.0f;
        } else {
            m.x = ((unsigned)(gx + 0) < (unsigned)W) ? src[0] * 2.0f - 1.0f : 0.0f;
            m.y = ((unsigned)(gx + 1) < (unsigned)W) ? src[1] * 2.0f - 1.0f : 0.0f;
            m.z = ((unsigned)(gx + 2) < (unsigned)W) ? src[2] * 2.0f - 1.0f : 0.0f;
            m.w = ((unsigned)(gx + 3) < (unsigned)W) ? src[3] * 2.0f - 1.0f : 0.0f;
        }
        const int c = c4 * 4;
        st[c + 0][row] = m.x;
        st[c + 1][row] = m.y;
        st[c + 2][row] = m.z;
        st[c + 3][row] = m.w;
    }
    __syncthreads();

    const int tx = tid & 63;    // row lane (stride-1 LDS reads)
    const int ty = tid >> 6;    // col strip 0..3
    float acc[R];
#pragma unroll
    for (int o = 0; o < R; ++o) acc[o] = 0.0f;

    const int cbase = ty * R + 1;
#pragma unroll
    for (int t = 0; t < R + KS - 1; ++t) {
        float v = st[cbase + t][tx];
#pragma unroll
        for (int o = 0; o < R; ++o) {
            int k = t - o;
            if (k >= 0 && k < KS) acc[o] += WT.w[k] * v;
        }
    }
    __syncthreads();

    // transpose outputs back through LDS (reuse st) for coalesced stores
    float* so = &st[0][0];      // logical [64][65]
#pragma unroll
    for (int o = 0; o < R; ++o)
        so[tx * 65 + ty * R + o] = acc[o];
    __syncthreads();
    for (int i = tid; i < 64 * 16; i += 256) {
        int row = i >> 4;
        int c4 = i & 15;
        const float* sp = &so[row * 65 + c4 * 4];
        float4 v; v.x = sp[0]; v.y = sp[1]; v.z = sp[2]; v.w = sp[3];
        *(float4*)(tmp + base + (y0 + row) * W + x0 + c4 * 4) = v;
    }
}

// ---------------------------------------------------------------------------
// Per-pixel sampler (fallback kernels only)
// ---------------------------------------------------------------------------
__device__ __forceinline__ void sample_and_store(const float* __restrict__ img,
                                                 float* __restrict__ out,
                                                 int ibase, int HW,
                                                 int y, int x, int H, int W,
                                                 float dx, float dy) {
    const float gx = -1.0f + (float)x * (2.0f / (W - 1));
    const float gy = -1.0f + (float)y * (2.0f / (H - 1));
    const float sx = fminf(fmaxf(gx + dx, -1.0f), 1.0f);
    const float sy = fminf(fmaxf(gy + dy, -1.0f), 1.0f);
    const float ix = ((sx + 1.0f) * (float)W - 1.0f) * 0.5f;
    const float iy = ((sy + 1.0f) * (float)H - 1.0f) * 0.5f;
    const float ix0f = floorf(ix);
    const float iy0f = floorf(iy);
    const int ix0 = (int)ix0f;
    const int iy0 = (int)iy0f;
    const float wx = ix - ix0f;
    const float wy = iy - iy0f;

    const float bx0 = (ix0 == -1) ? wx : ((ix0 <= W - 2) ? (1.0f - wx) : 0.0f);
    const float bx1 = (ix0 >= W - 1) ? (1.0f - wx) : ((ix0 >= 0) ? wx : 0.0f);
    const float ay0 = (iy0 >= 0) ? (1.0f - wy) : 0.0f;
    const float ay1 = (iy0 <= H - 2) ? wy : 0.0f;
    const int px = min(max(ix0, 0), W - 2);
    const int it = min(max(iy0, 0), H - 1) * W + px;
    const int ib = min(max(iy0 + 1, 0), H - 1) * W + px;
    const int orem = y * W + x;

#pragma unroll
    for (int c = 0; c < 3; ++c) {
        const float* p = img + ibase + c * HW;
        f32x2 t, bt;
        __builtin_memcpy(&t,  p + it, 8);
        __builtin_memcpy(&bt, p + ib, 8);
        const float rt = t.x * bx0 + t.y * bx1;
        const float rb = bt.x * bx0 + bt.y * bx1;
        __builtin_nontemporal_store(rt * ay0 + rb * ay1, &out[ibase + c * HW + orem]);
    }
}

// shared conv body (compile-time indices; s is the LDS tile)
__device__ __forceinline__ void conv_col(const float (*__restrict__ s)[64],
                                         int yr, int tx, float acc[RV]) {
#pragma unroll
    for (int o = 0; o < RV; ++o) acc[o] = 0.0f;
#pragma unroll
    for (int t = 0; t < RV + KS - 1; ++t) {
        float v = s[yr + t][tx];
#pragma unroll
        for (int o = 0; o < RV; ++o) {
            int k = t - o;
            if (k >= 0 && k < KS) acc[o] += WT.w[k] * v;
        }
    }
}

// ---------------------------------------------------------------------------
// FUSED vertical blur + warp: tmp[B,2,H,W] -> disp[B,H,W,2] + warped[B,3,H,W]
// Block = 32 rows x 64 cols (RV=8, 24 KB LDS); chunked XCD swizzle; batched
// gather. T14 async-STAGE: ch1's staging loads are ISSUED before ch0's conv
// (latency hidden under ~2000 cyc of FMAs), written to LDS after; 3 barriers.
// (R22 verified best: 56 us profiled, 33% occupancy, VGPR 60. R23's dual-
// buffer variant regressed — 48 KB LDS halves blocks/CU, which matters more
// than the 2 barriers it saves.)
// ---------------------------------------------------------------------------
__global__ __launch_bounds__(256) void vblur_warp_kernel(const float* __restrict__ tmp,
                                                         const float* __restrict__ img,
                                                         float* __restrict__ disp,
                                                         float* __restrict__ warped,
                                                         int H, int W) {
    constexpr int SROWS = 4 * RV + KS - 1;     // 94
    constexpr int NSTG  = (SROWS * 16 + 255) / 256;  // 6 float4 stage iters/thread
    __shared__ float s[SROWS][64];             // 24.06 KB
    const int tid = threadIdx.x;

    // chunked XCD swizzle: XCD k gets consecutive logical tiles (2 images)
    const int nx = gridDim.x, ny = gridDim.y;
    const int nwg = nx * ny * gridDim.z;           // 2048, % 8 == 0
    const int flat = blockIdx.x + nx * (blockIdx.y + ny * blockIdx.z);
    const int wg = (flat & 7) * (nwg >> 3) + (flat >> 3);
    const int xt = wg % nx;
    const int yt = (wg / nx) % ny;
    const int b  = wg / (nx * ny);

    const int x0 = xt * 64;
    const int y0 = yt * (4 * RV);
    const int tx = tid & 63;
    const int ty = tid >> 6;
    const int yr = ty * RV;
    const int HW = H * W;
    float4* s4 = (float4*)&s[0][0];

    // ---- stage ch0 ----
    {
        const int base = (b * 2 + 0) * HW;
        for (int i = tid; i < SROWS * 16; i += 256) {
            int row = i >> 4;
            int c4 = i & 15;
            int gy = y0 + row - PAD;
            float4 v = make_float4(0.0f, 0.0f, 0.0f, 0.0f);
            if (gy >= 0 && gy < H) v = *(const float4*)(tmp + base + gy * W + x0 + c4 * 4);
            s4[row * 16 + c4] = v;
        }
    }
    __syncthreads();

    // ---- T14: issue ch1's staging loads NOW (latency hides under conv ch0) ----
    float4 pre[NSTG];
    {
        const int base = (b * 2 + 1) * HW;
#pragma unroll
        for (int j = 0; j < NSTG; ++j) {
            const int i = tid + j * 256;
            float4 v = make_float4(0.0f, 0.0f, 0.0f, 0.0f);
            if (i < SROWS * 16) {
                int row = i >> 4;
                int c4 = i & 15;
                int gy = y0 + row - PAD;
                if (gy >= 0 && gy < H) v = *(const float4*)(tmp + base + gy * W + x0 + c4 * 4);
            }
            pre[j] = v;
        }
    }

    // ---- conv ch0 ----
    float acc0[RV], acc1[RV];
    conv_col(s, yr, tx, acc0);
    __syncthreads();            // everyone done reading ch0 tile

    // ---- write ch1 regs to LDS ----
#pragma unroll
    for (int j = 0; j < NSTG; ++j) {
        const int i = tid + j * 256;
        if (i < SROWS * 16) s4[i] = pre[j];
    }
    __syncthreads();

    // ---- conv ch1 ----
    conv_col(s, yr, tx, acc1);

    const int x = x0 + tx;
    const int ibase = b * 3 * HW;
    f32x2* disp2 = (f32x2*)disp;

    // ---- phase 1: all per-pixel params (no loads) ----
    float BX0[RV], BX1[RV], AY0[RV], AY1[RV];
    int IT[RV], IB[RV];
    const float gxn = -1.0f + (float)x * (2.0f / (W - 1));
#pragma unroll
    for (int o = 0; o < RV; ++o) {
        const int y = y0 + yr + o;
        const float dx = acc0[o];
        const float dy = acc1[o];
        f32x2 dv; dv.x = dx; dv.y = dy;
        __builtin_nontemporal_store(dv, &disp2[(b * H + y) * W + x]);

        const float gyn = -1.0f + (float)y * (2.0f / (H - 1));
        const float sx = fminf(fmaxf(gxn + dx, -1.0f), 1.0f);
        const float sy = fminf(fmaxf(gyn + dy, -1.0f), 1.0f);
        const float ix = ((sx + 1.0f) * (float)W - 1.0f) * 0.5f;
        const float iy = ((sy + 1.0f) * (float)H - 1.0f) * 0.5f;
        const float ix0f = floorf(ix);
        const float iy0f = floorf(iy);
        const int ix0 = (int)ix0f;
        const int iy0 = (int)iy0f;
        const float wx = ix - ix0f;
        const float wy = iy - iy0f;

        BX0[o] = (ix0 == -1) ? wx : ((ix0 <= W - 2) ? (1.0f - wx) : 0.0f);
        BX1[o] = (ix0 >= W - 1) ? (1.0f - wx) : ((ix0 >= 0) ? wx : 0.0f);
        AY0[o] = (iy0 >= 0) ? (1.0f - wy) : 0.0f;
        AY1[o] = (iy0 <= H - 2) ? wy : 0.0f;
        const int px = min(max(ix0, 0), W - 2);
        IT[o] = min(max(iy0, 0), H - 1) * W + px;
        IB[o] = min(max(iy0 + 1, 0), H - 1) * W + px;
    }

    // ---- phases 2+3 per channel: issue ALL 16 loads, then combine ----
#pragma unroll
    for (int c = 0; c < 3; ++c) {
        const float* p = img + ibase + c * HW;
        f32x2 T[RV], Bt[RV];
#pragma unroll
        for (int o = 0; o < RV; ++o) {
            __builtin_memcpy(&T[o],  p + IT[o], 8);
            __builtin_memcpy(&Bt[o], p + IB[o], 8);
        }
#pragma unroll
        for (int o = 0; o < RV; ++o) {
            const float rt = T[o].x * BX0[o] + T[o].y * BX1[o];
            const float rb = Bt[o].x * BX0[o] + Bt[o].y * BX1[o];
            const float v = rt * AY0[o] + rb * AY1[o];
            const int y = y0 + yr + o;
            __builtin_nontemporal_store(v, &warped[ibase + c * HW + y * W + x]);
        }
    }
}

// ---------------------------------------------------------------------------
// Fallback pair (used only if d_ws is too small to hold tmp)
// ---------------------------------------------------------------------------
__global__ __launch_bounds__(256) void vblur_kernel(const float* __restrict__ tmp,
                                                    float* __restrict__ disp,
                                                    int H, int W) {
    __shared__ float s[126][64];
    const int tid = threadIdx.x;
    const int x0 = blockIdx.x * 64;
    const int y0 = blockIdx.y * 64;
    const int b = blockIdx.z;
    const int tx = tid & 63;
    const int ty = tid >> 6;
    const int yr = ty * R;
    float acc0[R], acc1[R];

#pragma unroll
    for (int ch = 0; ch < 2; ++ch) {
        __syncthreads();
        const int base = (b * 2 + ch) * H * W;
        float2* s2 = (float2*)&s[0][0];
        for (int i = tid; i < 126 * 32; i += 256) {
            int row = i >> 5;
            int c2 = i & 31;
            int gy = y0 + row - PAD;
            float2 v = make_float2(0.0f, 0.0f);
            if (gy >= 0 && gy < H) v = *(const float2*)(tmp + base + gy * W + x0 + c2 * 2);
            s2[row * 32 + c2] = v;
        }
        __syncthreads();

        float* acc = (ch == 0) ? acc0 : acc1;
#pragma unroll
        for (int o = 0; o < R; ++o) acc[o] = 0.0f;
#pragma unroll
        for (int t = 0; t < R + KS - 1; ++t) {
            float v = s[yr + t][tx];
#pragma unroll
            for (int o = 0; o < R; ++o) {
                int k = t - o;
                if (k >= 0 && k < KS) acc[o] += WT.w[k] * v;
            }
        }
    }

    float2* disp2 = (float2*)disp;
#pragma unroll
    for (int o = 0; o < R; ++o) {
        int y = y0 + yr + o;
        disp2[(b * H + y) * W + x0 + tx] = make_float2(acc0[o], acc1[o]);
    }
}

__global__ __launch_bounds__(256) void warp_kernel(const float* __restrict__ img,
                                                   const float* __restrict__ disp,
                                                   float* __restrict__ out,
                                                   int B, int H, int W) {
    const int HW = H * W;
    const int idx = blockIdx.x * 256 + threadIdx.x;
    if (idx >= B * HW) return;
    const int b = idx / HW;
    const int rem = idx - b * HW;
    const int y = rem / W;
    const int x = rem - y * W;
    const float2 d = ((const float2*)disp)[idx];
    sample_and_store(img, out, b * 3 * HW, HW, y, x, H, W, d.x, d.y);
}

// ---------------------------------------------------------------------------
extern "C" void kernel_launch(void* const* d_in, const int* in_sizes, int n_in,
                              void* d_out, int out_size, void* d_ws, size_t ws_size,
                              hipStream_t stream) {
    const float* input = (const float*)d_in[0];   // [16,3,512,512]
    const float* noise = (const float*)d_in[1];   // [16,2,512,512]
    float* out = (float*)d_out;

    const int B = 16, H = 512, W = 512;
    const int warped_elems = B * 3 * H * W;
    const size_t tmp_bytes = (size_t)B * 2 * H * W * sizeof(float);  // 33.5 MB

    float* warped = out;
    float* disp   = out + warped_elems;           // [B,H,W,2]

    const bool ws_ok = (ws_size >= tmp_bytes);
    float* tmp = ws_ok ? (float*)d_ws : warped;

    {
        dim3 grid(W / 64, H / 64, B * 2);
        hblur_kernel<<<grid, 256, 0, stream>>>(noise, tmp, H, W);
    }
    if (ws_ok) {
        // fused vblur + warp: disp never round-trips to memory as an input
        dim3 grid(W / 64, H / (4 * RV), B);
        vblur_warp_kernel<<<grid, 256, 0, stream>>>(tmp, input, disp, warped, H, W);
    } else {
        // tmp aliases the warped region: must keep vblur (reads tmp) strictly
        // before warp (writes warped)
        dim3 grid(W / 64, H / 64, B);
        vblur_kernel<<<grid, 256, 0, stream>>>(tmp, disp, H, W);
        int nthreads = B * H * W;
        warp_kernel<<<(nthreads + 255) / 256, 256, 0, stream>>>(input, disp, warped, B, H, W);
    }
}

// Round 25
// 60.679 us; speedup vs baseline: 1.1087x; 1.0170x over previous
//
#include <hip/hip_runtime.h>

#define KS 63
#define PAD 31
#define R 16   // hblur / fallback tile factor
#define RV 8   // fused vblur+warp: outputs per thread (y direction)
#define TC 32  // fused vblur+warp: tile cols (tall-narrow tile)

typedef float f32x2 __attribute__((ext_vector_type(2)));

// ---------------------------------------------------------------------------
// Compile-time Gaussian weights (normalized, double precision -> f32 literals)
// ---------------------------------------------------------------------------
constexpr double cexp_neg(double t) {  // e^{-t}, t in [0, 0.47]
    double s = 1.0, term = 1.0;
    for (int i = 1; i < 24; ++i) { term *= (-t) / (double)i; s += term; }
    return s;
}
struct WTab { float w[KS]; };
constexpr WTab make_wtab() {
    WTab r{};
    double v[KS] = {}; double s = 0.0;
    for (int i = 0; i < KS; ++i) {
        double x = (double)(i - PAD);
        v[i] = cexp_neg((x * x) / 2048.0);   // 2*sigma^2 = 2048
        s += v[i];
    }
    for (int i = 0; i < KS; ++i) r.w[i] = (float)(v[i] / s);
    return r;
}
constexpr WTab WT = make_wtab();

// ---------------------------------------------------------------------------
// Horizontal blur, transposed-tile. Block = 64 rows x 64 out cols.
// float4 staging (8 loads/thread). Zero-padding applies AFTER the (n*2-1)
// map — OOB halo must be 0, not -1. (R15/R16 proven version, byte-identical)
// ---------------------------------------------------------------------------
__global__ __launch_bounds__(256) void hblur_kernel(const float* __restrict__ noise,
                                                    float* __restrict__ tmp,
                                                    int H, int W) {
    __shared__ float st[128][65];   // [c][row]; input col = x0-32+c
    const int tid = threadIdx.x;
    const int x0 = blockIdx.x * 64;
    const int y0 = blockIdx.y * 64;
    const int bc = blockIdx.z;              // b*2 + ch
    const int base = bc * H * W;

    // stage 64 rows x 128 cols as float4 (8/thread), transposed into LDS
    for (int i = tid; i < 64 * 32; i += 256) {
        int row = i >> 5;
        int c4 = i & 31;                    // covers input cols c4*4 .. c4*4+3
        int gx = x0 - 32 + c4 * 4;          // multiple of 4 -> aligned or fully OOB
        const float* src = noise + base + (y0 + row) * W + gx;
        float4 m;
        if (gx >= 0 && gx <= W - 4) {
            float4 v = *(const float4*)src;
            m.x = v.x * 2.0f - 1.0f;
            m.y = v.y * 2.0f - 1.0f;
            m.z = v.z * 2.0f - 1.0f;
            m.w = v.w * 2.0f - 1.0f;
        } else {
            m.x = ((unsigned)(gx + 0) < (unsigned)W) ? src[0] * 2.0f - 1.0f : 0.0f;
            m.y = ((unsigned)(gx + 1) < (unsigned)W) ? src[1] * 2.0f - 1.0f : 0.0f;
            m.z = ((unsigned)(gx + 2) < (unsigned)W) ? src[2] * 2.0f - 1.0f : 0.0f;
            m.w = ((unsigned)(gx + 3) < (unsigned)W) ? src[3] * 2.0f - 1.0f : 0.0f;
        }
        const int c = c4 * 4;
        st[c + 0][row] = m.x;
        st[c + 1][row] = m.y;
        st[c + 2][row] = m.z;
        st[c + 3][row] = m.w;
    }
    __syncthreads();

    const int tx = tid & 63;    // row lane (stride-1 LDS reads)
    const int ty = tid >> 6;    // col strip 0..3
    float acc[R];
#pragma unroll
    for (int o = 0; o < R; ++o) acc[o] = 0.0f;

    const int cbase = ty * R + 1;
#pragma unroll
    for (int t = 0; t < R + KS - 1; ++t) {
        float v = st[cbase + t][tx];
#pragma unroll
        for (int o = 0; o < R; ++o) {
            int k = t - o;
            if (k >= 0 && k < KS) acc[o] += WT.w[k] * v;
        }
    }
    __syncthreads();

    // transpose outputs back through LDS (reuse st) for coalesced stores
    float* so = &st[0][0];      // logical [64][65]
#pragma unroll
    for (int o = 0; o < R; ++o)
        so[tx * 65 + ty * R + o] = acc[o];
    __syncthreads();
    for (int i = tid; i < 64 * 16; i += 256) {
        int row = i >> 4;
        int c4 = i & 15;
        const float* sp = &so[row * 65 + c4 * 4];
        float4 v; v.x = sp[0]; v.y = sp[1]; v.z = sp[2]; v.w = sp[3];
        *(float4*)(tmp + base + (y0 + row) * W + x0 + c4 * 4) = v;
    }
}

// ---------------------------------------------------------------------------
// Per-pixel sampler (fallback kernels only)
// ---------------------------------------------------------------------------
__device__ __forceinline__ void sample_and_store(const float* __restrict__ img,
                                                 float* __restrict__ out,
                                                 int ibase, int HW,
                                                 int y, int x, int H, int W,
                                                 float dx, float dy) {
    const float gx = -1.0f + (float)x * (2.0f / (W - 1));
    const float gy = -1.0f + (float)y * (2.0f / (H - 1));
    const float sx = fminf(fmaxf(gx + dx, -1.0f), 1.0f);
    const float sy = fminf(fmaxf(gy + dy, -1.0f), 1.0f);
    const float ix = ((sx + 1.0f) * (float)W - 1.0f) * 0.5f;
    const float iy = ((sy + 1.0f) * (float)H - 1.0f) * 0.5f;
    const float ix0f = floorf(ix);
    const float iy0f = floorf(iy);
    const int ix0 = (int)ix0f;
    const int iy0 = (int)iy0f;
    const float wx = ix - ix0f;
    const float wy = iy - iy0f;

    const float bx0 = (ix0 == -1) ? wx : ((ix0 <= W - 2) ? (1.0f - wx) : 0.0f);
    const float bx1 = (ix0 >= W - 1) ? (1.0f - wx) : ((ix0 >= 0) ? wx : 0.0f);
    const float ay0 = (iy0 >= 0) ? (1.0f - wy) : 0.0f;
    const float ay1 = (iy0 <= H - 2) ? wy : 0.0f;
    const int px = min(max(ix0, 0), W - 2);
    const int it = min(max(iy0, 0), H - 1) * W + px;
    const int ib = min(max(iy0 + 1, 0), H - 1) * W + px;
    const int orem = y * W + x;

#pragma unroll
    for (int c = 0; c < 3; ++c) {
        const float* p = img + ibase + c * HW;
        f32x2 t, bt;
        __builtin_memcpy(&t,  p + it, 8);
        __builtin_memcpy(&bt, p + ib, 8);
        const float rt = t.x * bx0 + t.y * bx1;
        const float rb = bt.x * bx0 + bt.y * bx1;
        __builtin_nontemporal_store(rt * ay0 + rb * ay1, &out[ibase + c * HW + orem]);
    }
}

// shared conv body (compile-time indices; s is the LDS tile, TC cols wide)
__device__ __forceinline__ void conv_col(const float (*__restrict__ s)[TC],
                                         int yr, int tx, float acc[RV]) {
#pragma unroll
    for (int o = 0; o < RV; ++o) acc[o] = 0.0f;
#pragma unroll
    for (int t = 0; t < RV + KS - 1; ++t) {
        float v = s[yr + t][tx];
#pragma unroll
        for (int o = 0; o < RV; ++o) {
            int k = t - o;
            if (k >= 0 && k < KS) acc[o] += WT.w[k] * v;
        }
    }
}

// ---------------------------------------------------------------------------
// FUSED vertical blur + warp: tmp[B,2,H,W] -> disp[B,H,W,2] + warped[B,3,H,W]
// R25: tall-narrow tile — 64 rows x 32 cols, 8 row-groups (ty 0..7), LDS
// 126x32 = 16.1 KB -> occupancy cap rises 24 -> 32 waves/CU, and tmp halo
// re-read drops 2.94x -> 1.97x. Same T14 async-STAGE (ch1 prefetched into
// regs under conv ch0), 3 barriers, batched per-channel gather, XCD swizzle.
// ---------------------------------------------------------------------------
__global__ __launch_bounds__(256) void vblur_warp_kernel(const float* __restrict__ tmp,
                                                         const float* __restrict__ img,
                                                         float* __restrict__ disp,
                                                         float* __restrict__ warped,
                                                         int H, int W) {
    constexpr int ROWS  = 8 * RV;              // 64 output rows
    constexpr int SROWS = ROWS + KS - 1;       // 126
    constexpr int NF4   = SROWS * (TC / 4);    // 1008 float4 slots
    constexpr int NSTG  = (NF4 + 255) / 256;   // 4 stage iters/thread
    __shared__ float s[SROWS][TC];             // 16.13 KB
    const int tid = threadIdx.x;

    // chunked XCD swizzle: XCD k gets consecutive logical tiles (2 images)
    const int nx = gridDim.x, ny = gridDim.y;
    const int nwg = nx * ny * gridDim.z;           // 2048, % 8 == 0
    const int flat = blockIdx.x + nx * (blockIdx.y + ny * blockIdx.z);
    const int wg = (flat & 7) * (nwg >> 3) + (flat >> 3);
    const int xt = wg % nx;
    const int yt = (wg / nx) % ny;
    const int b  = wg / (nx * ny);

    const int x0 = xt * TC;
    const int y0 = yt * ROWS;
    const int tx = tid & (TC - 1);   // col 0..31
    const int ty = tid >> 5;         // row group 0..7
    const int yr = ty * RV;
    const int HW = H * W;
    float4* s4 = (float4*)&s[0][0];

    // ---- stage ch0 ----
    {
        const int base = (b * 2 + 0) * HW;
        for (int i = tid; i < NF4; i += 256) {
            int row = i >> 3;            // 8 float4 per row
            int c4 = i & 7;
            int gy = y0 + row - PAD;
            float4 v = make_float4(0.0f, 0.0f, 0.0f, 0.0f);
            if (gy >= 0 && gy < H) v = *(const float4*)(tmp + base + gy * W + x0 + c4 * 4);
            s4[i] = v;
        }
    }
    __syncthreads();

    // ---- T14: issue ch1's staging loads NOW (latency hides under conv ch0) ----
    float4 pre[NSTG];
    {
        const int base = (b * 2 + 1) * HW;
#pragma unroll
        for (int j = 0; j < NSTG; ++j) {
            const int i = tid + j * 256;
            float4 v = make_float4(0.0f, 0.0f, 0.0f, 0.0f);
            if (i < NF4) {
                int row = i >> 3;
                int c4 = i & 7;
                int gy = y0 + row - PAD;
                if (gy >= 0 && gy < H) v = *(const float4*)(tmp + base + gy * W + x0 + c4 * 4);
            }
            pre[j] = v;
        }
    }

    // ---- conv ch0 ----
    float acc0[RV], acc1[RV];
    conv_col(s, yr, tx, acc0);
    __syncthreads();            // everyone done reading ch0 tile

    // ---- write ch1 regs to LDS ----
#pragma unroll
    for (int j = 0; j < NSTG; ++j) {
        const int i = tid + j * 256;
        if (i < NF4) s4[i] = pre[j];
    }
    __syncthreads();

    // ---- conv ch1 ----
    conv_col(s, yr, tx, acc1);

    const int x = x0 + tx;
    const int ibase = b * 3 * HW;
    f32x2* disp2 = (f32x2*)disp;

    // ---- phase 1: all per-pixel params (no loads) ----
    float BX0[RV], BX1[RV], AY0[RV], AY1[RV];
    int IT[RV], IB[RV];
    const float gxn = -1.0f + (float)x * (2.0f / (W - 1));
#pragma unroll
    for (int o = 0; o < RV; ++o) {
        const int y = y0 + yr + o;
        const float dx = acc0[o];
        const float dy = acc1[o];
        f32x2 dv; dv.x = dx; dv.y = dy;
        __builtin_nontemporal_store(dv, &disp2[(b * H + y) * W + x]);

        const float gyn = -1.0f + (float)y * (2.0f / (H - 1));
        const float sx = fminf(fmaxf(gxn + dx, -1.0f), 1.0f);
        const float sy = fminf(fmaxf(gyn + dy, -1.0f), 1.0f);
        const float ix = ((sx + 1.0f) * (float)W - 1.0f) * 0.5f;
        const float iy = ((sy + 1.0f) * (float)H - 1.0f) * 0.5f;
        const float ix0f = floorf(ix);
        const float iy0f = floorf(iy);
        const int ix0 = (int)ix0f;
        const int iy0 = (int)iy0f;
        const float wx = ix - ix0f;
        const float wy = iy - iy0f;

        BX0[o] = (ix0 == -1) ? wx : ((ix0 <= W - 2) ? (1.0f - wx) : 0.0f);
        BX1[o] = (ix0 >= W - 1) ? (1.0f - wx) : ((ix0 >= 0) ? wx : 0.0f);
        AY0[o] = (iy0 >= 0) ? (1.0f - wy) : 0.0f;
        AY1[o] = (iy0 <= H - 2) ? wy : 0.0f;
        const int px = min(max(ix0, 0), W - 2);
        IT[o] = min(max(iy0, 0), H - 1) * W + px;
        IB[o] = min(max(iy0 + 1, 0), H - 1) * W + px;
    }

    // ---- phases 2+3 per channel: issue ALL 16 loads, then combine ----
#pragma unroll
    for (int c = 0; c < 3; ++c) {
        const float* p = img + ibase + c * HW;
        f32x2 T[RV], Bt[RV];
#pragma unroll
        for (int o = 0; o < RV; ++o) {
            __builtin_memcpy(&T[o],  p + IT[o], 8);
            __builtin_memcpy(&Bt[o], p + IB[o], 8);
        }
#pragma unroll
        for (int o = 0; o < RV; ++o) {
            const float rt = T[o].x * BX0[o] + T[o].y * BX1[o];
            const float rb = Bt[o].x * BX0[o] + Bt[o].y * BX1[o];
            const float v = rt * AY0[o] + rb * AY1[o];
            const int y = y0 + yr + o;
            __builtin_nontemporal_store(v, &warped[ibase + c * HW + y * W + x]);
        }
    }
}

// ---------------------------------------------------------------------------
// Fallback pair (used only if d_ws is too small to hold tmp)
// ---------------------------------------------------------------------------
__global__ __launch_bounds__(256) void vblur_kernel(const float* __restrict__ tmp,
                                                    float* __restrict__ disp,
                                                    int H, int W) {
    __shared__ float s[126][64];
    const int tid = threadIdx.x;
    const int x0 = blockIdx.x * 64;
    const int y0 = blockIdx.y * 64;
    const int b = blockIdx.z;
    const int tx = tid & 63;
    const int ty = tid >> 6;
    const int yr = ty * R;
    float acc0[R], acc1[R];

#pragma unroll
    for (int ch = 0; ch < 2; ++ch) {
        __syncthreads();
        const int base = (b * 2 + ch) * H * W;
        float2* s2 = (float2*)&s[0][0];
        for (int i = tid; i < 126 * 32; i += 256) {
            int row = i >> 5;
            int c2 = i & 31;
            int gy = y0 + row - PAD;
            float2 v = make_float2(0.0f, 0.0f);
            if (gy >= 0 && gy < H) v = *(const float2*)(tmp + base + gy * W + x0 + c2 * 2);
            s2[row * 32 + c2] = v;
        }
        __syncthreads();

        float* acc = (ch == 0) ? acc0 : acc1;
#pragma unroll
        for (int o = 0; o < R; ++o) acc[o] = 0.0f;
#pragma unroll
        for (int t = 0; t < R + KS - 1; ++t) {
            float v = s[yr + t][tx];
#pragma unroll
            for (int o = 0; o < R; ++o) {
                int k = t - o;
                if (k >= 0 && k < KS) acc[o] += WT.w[k] * v;
            }
        }
    }

    float2* disp2 = (float2*)disp;
#pragma unroll
    for (int o = 0; o < R; ++o) {
        int y = y0 + yr + o;
        disp2[(b * H + y) * W + x0 + tx] = make_float2(acc0[o], acc1[o]);
    }
}

__global__ __launch_bounds__(256) void warp_kernel(const float* __restrict__ img,
                                                   const float* __restrict__ disp,
                                                   float* __restrict__ out,
                                                   int B, int H, int W) {
    const int HW = H * W;
    const int idx = blockIdx.x * 256 + threadIdx.x;
    if (idx >= B * HW) return;
    const int b = idx / HW;
    const int rem = idx - b * HW;
    const int y = rem / W;
    const int x = rem - y * W;
    const float2 d = ((const float2*)disp)[idx];
    sample_and_store(img, out, b * 3 * HW, HW, y, x, H, W, d.x, d.y);
}

// ---------------------------------------------------------------------------
extern "C" void kernel_launch(void* const* d_in, const int* in_sizes, int n_in,
                              void* d_out, int out_size, void* d_ws, size_t ws_size,
                              hipStream_t stream) {
    const float* input = (const float*)d_in[0];   // [16,3,512,512]
    const float* noise = (const float*)d_in[1];   // [16,2,512,512]
    float* out = (float*)d_out;

    const int B = 16, H = 512, W = 512;
    const int warped_elems = B * 3 * H * W;
    const size_t tmp_bytes = (size_t)B * 2 * H * W * sizeof(float);  // 33.5 MB

    float* warped = out;
    float* disp   = out + warped_elems;           // [B,H,W,2]

    const bool ws_ok = (ws_size >= tmp_bytes);
    float* tmp = ws_ok ? (float*)d_ws : warped;

    {
        dim3 grid(W / 64, H / 64, B * 2);
        hblur_kernel<<<grid, 256, 0, stream>>>(noise, tmp, H, W);
    }
    if (ws_ok) {
        // fused vblur + warp: disp never round-trips to memory as an input
        dim3 grid(W / TC, H / (8 * RV), B);      // (16, 8, 16) = 2048 blocks
        vblur_warp_kernel<<<grid, 256, 0, stream>>>(tmp, input, disp, warped, H, W);
    } else {
        // tmp aliases the warped region: must keep vblur (reads tmp) strictly
        // before warp (writes warped)
        dim3 grid(W / 64, H / 64, B);
        vblur_kernel<<<grid, 256, 0, stream>>>(tmp, disp, H, W);
        int nthreads = B * H * W;
        warp_kernel<<<(nthreads + 255) / 256, 256, 0, stream>>>(input, disp, warped, B, H, W);
    }
}